// Round 12
// baseline (507.037 us; speedup 1.0000x reference)
//
#include <hip/hip_runtime.h>
#include <math.h>

#define BATCH 256
#define CH 512
#define SE_CH 32
#define HW 1024            // 32*32 floats per plane
#define NBLK 512           // 2 blocks/CU, exactly machine-filling -> co-resident
#define NTHR 256           // 4 waves
#define ROUNDS 8           // 4096 units / 512 blocks
#define UPB 16             // units (blocks) per batch
#define CPU_ 32            // channels per unit

typedef float f32x4 __attribute__((ext_vector_type(4)));

#define FOR8(X) X(0) X(1) X(2) X(3) X(4) X(5) X(6) X(7)

// One-pass SE, register-resident, correctly sized for the 2048-VGPR/CU file:
// 512 blocks x 256 thr (8 waves/CU -> 256 VGPR budget/wave). Each block per
// round holds 32 planes (128 KB) in 128 data VGPRs/thread, exchanges 32-float
// FC1 partials with its 15 sibling blocks (same round, co-resident), applies
// from registers. x read once, out written once: 1.07 GB total HBM.
__global__ __launch_bounds__(NTHR, 2) void se_regpipe(
        const float* __restrict__ x,
        float* __restrict__ out,
        const float* __restrict__ fc1_w,   // [SE_CH][CH]
        const float* __restrict__ fc1_b,   // [SE_CH]
        const float* __restrict__ fc2_w,   // [2*CH][SE_CH]
        const float* __restrict__ fc2_b,   // [2*CH]
        float* __restrict__ yacc,          // [BATCH][SE_CH], zeroed per call
        int* __restrict__ flags) {         // [BATCH], zeroed per call
    const int t = threadIdx.x;
    const int w = t >> 6;          // wave 0..3
    const int lane = t & 63;
    const int bid = (int)blockIdx.x;

    __shared__ float m[CPU_];      // this unit's 32 plane means
    __shared__ float sev[SE_CH];   // relu(FC1)
    __shared__ float sc[CPU_];     // sigmoid(scale) per local channel
    __shared__ float bo[CPU_];     // bias per local channel

#pragma clang loop unroll(disable)
    for (int r = 0; r < ROUNDS; ++r) {
        const int u = r * NBLK + bid;              // unit 0..4095
        const int b = u >> 4;                      // batch
        const int c0 = (u & 15) * CPU_;            // first channel of unit
        const size_t base = ((size_t)b * CH + c0) * HW;
        const f32x4* xb = (const f32x4*)(x + base);
        f32x4* ob = (f32x4*)(out + base);

        // ---- load 32 planes: wave w owns planes w*8..w*8+7;
        //      lane holds f32x4 slots {lane, lane+64, lane+128, lane+192} ----
#define DECLP(i) f32x4 d##i##_0, d##i##_1, d##i##_2, d##i##_3;
        FOR8(DECLP)
#undef DECLP
#define LOADP(i) \
        d##i##_0 = __builtin_nontemporal_load(&xb[(size_t)(w * 8 + (i)) * 256 +   0 + lane]); \
        d##i##_1 = __builtin_nontemporal_load(&xb[(size_t)(w * 8 + (i)) * 256 +  64 + lane]); \
        d##i##_2 = __builtin_nontemporal_load(&xb[(size_t)(w * 8 + (i)) * 256 + 128 + lane]); \
        d##i##_3 = __builtin_nontemporal_load(&xb[(size_t)(w * 8 + (i)) * 256 + 192 + lane]);
        FOR8(LOADP)
#undef LOADP

        // ---- per-plane means: 8 independent 64-lane xor reduces ----
#define MEANP(i) { \
        f32x4 s4 = (d##i##_0 + d##i##_1) + (d##i##_2 + d##i##_3); \
        float s = (s4.x + s4.y) + (s4.z + s4.w); \
        s += __shfl_xor(s, 32, 64); s += __shfl_xor(s, 16, 64); \
        s += __shfl_xor(s, 8, 64);  s += __shfl_xor(s, 4, 64); \
        s += __shfl_xor(s, 2, 64);  s += __shfl_xor(s, 1, 64); \
        if (lane == 0) m[w * 8 + (i)] = s * (1.0f / 1024.0f); }
        FOR8(MEANP)
#undef MEANP

        // ---- pin the data registers: forbid rematerialization/sinking ----
#define PINP(i) asm volatile("" : "+v"(d##i##_0), "+v"(d##i##_1), \
                                  "+v"(d##i##_2), "+v"(d##i##_3));
        FOR8(PINP)
#undef PINP
        __syncthreads();

        // ---- FC1 partial over this unit's 32 channels ----
        // o = t>>3 (0..31), p3 = t&7 -> 4 channels each, reduce over 8 lanes.
        {
            const int o = t >> 3;
            const int p3 = t & 7;
            const float* wr = fc1_w + (size_t)o * CH + c0 + p3 * 4;
            const float* mr = m + p3 * 4;
            float acc = wr[0] * mr[0] + wr[1] * mr[1]
                      + wr[2] * mr[2] + wr[3] * mr[3];
            acc += __shfl_xor(acc, 4, 8);
            acc += __shfl_xor(acc, 2, 8);
            acc += __shfl_xor(acc, 1, 8);
            if (p3 == 0)
                __hip_atomic_fetch_add(&yacc[b * SE_CH + o], acc,
                                       __ATOMIC_RELAXED, __HIP_MEMORY_SCOPE_AGENT);
        }
        __syncthreads();   // all waves' atomics issued & drained

        // ---- cross-block exchange: 16 sibling blocks, same round ----
        if (t == 0) {
            __hip_atomic_fetch_add(&flags[b], 1,
                                   __ATOMIC_RELEASE, __HIP_MEMORY_SCOPE_AGENT);
            while (__hip_atomic_load(&flags[b], __ATOMIC_ACQUIRE,
                                     __HIP_MEMORY_SCOPE_AGENT) < UPB)
                __builtin_amdgcn_s_sleep(2);
        }
        __syncthreads();

        // ---- finish FC1 (bias + relu) ----
        if (t < SE_CH) {
            float y = __hip_atomic_load(&yacc[b * SE_CH + t],
                                        __ATOMIC_RELAXED, __HIP_MEMORY_SCOPE_AGENT);
            sev[t] = fmaxf(y + fc1_b[t], 0.0f);
        }
        __syncthreads();

        // ---- FC2 for this unit's 32 channels (64 rows x dot-32) ----
        // row_id = t>>2 (0..63), kq = t&3 -> 8 k each, reduce over 4 lanes.
        {
            const int row_id = t >> 2;
            const int kq = t & 3;
            const int grow = (row_id < CPU_) ? (c0 + row_id)
                                             : (CH + c0 + row_id - CPU_);
            const float* wr = fc2_w + (size_t)grow * SE_CH + kq * 8;
            const float* sv = sev + kq * 8;
            float acc = 0.0f;
#pragma unroll
            for (int kk = 0; kk < 8; ++kk)
                acc = fmaf(wr[kk], sv[kk], acc);
            acc += __shfl_xor(acc, 2, 4);
            acc += __shfl_xor(acc, 1, 4);
            if (kq == 0) {
                acc += fc2_b[grow];
                if (row_id < CPU_)
                    sc[row_id] = 1.0f / (1.0f + expf(-acc));
                else
                    bo[row_id - CPU_] = acc;
            }
        }
        __syncthreads();

        // ---- apply from registers, nontemporal store ----
#define APPLYP(i) { \
        const float s_ = sc[w * 8 + (i)]; \
        const float b_ = bo[w * 8 + (i)]; \
        f32x4 rr; \
        rr.x = fmaf(d##i##_0.x, s_, b_); rr.y = fmaf(d##i##_0.y, s_, b_); \
        rr.z = fmaf(d##i##_0.z, s_, b_); rr.w = fmaf(d##i##_0.w, s_, b_); \
        __builtin_nontemporal_store(rr, &ob[(size_t)(w * 8 + (i)) * 256 +   0 + lane]); \
        rr.x = fmaf(d##i##_1.x, s_, b_); rr.y = fmaf(d##i##_1.y, s_, b_); \
        rr.z = fmaf(d##i##_1.z, s_, b_); rr.w = fmaf(d##i##_1.w, s_, b_); \
        __builtin_nontemporal_store(rr, &ob[(size_t)(w * 8 + (i)) * 256 +  64 + lane]); \
        rr.x = fmaf(d##i##_2.x, s_, b_); rr.y = fmaf(d##i##_2.y, s_, b_); \
        rr.z = fmaf(d##i##_2.z, s_, b_); rr.w = fmaf(d##i##_2.w, s_, b_); \
        __builtin_nontemporal_store(rr, &ob[(size_t)(w * 8 + (i)) * 256 + 128 + lane]); \
        rr.x = fmaf(d##i##_3.x, s_, b_); rr.y = fmaf(d##i##_3.y, s_, b_); \
        rr.z = fmaf(d##i##_3.z, s_, b_); rr.w = fmaf(d##i##_3.w, s_, b_); \
        __builtin_nontemporal_store(rr, &ob[(size_t)(w * 8 + (i)) * 256 + 192 + lane]); }
        FOR8(APPLYP)
#undef APPLYP
        // No trailing barrier needed: next round's m-writes are separated from
        // this round's m-reads by the post-mean barrier, and apply reads only
        // sc/bo, which next round rewrites only after two further barriers.
    }
}

extern "C" void kernel_launch(void* const* d_in, const int* in_sizes, int n_in,
                              void* d_out, int out_size, void* d_ws, size_t ws_size,
                              hipStream_t stream) {
    const float* x     = (const float*)d_in[0];
    const float* fc1_w = (const float*)d_in[1];
    const float* fc1_b = (const float*)d_in[2];
    const float* fc2_w = (const float*)d_in[3];
    const float* fc2_b = (const float*)d_in[4];
    float* out = (float*)d_out;

    float* yacc = (float*)d_ws;                                         // 32 KB
    int* flags  = (int*)((char*)d_ws + BATCH * SE_CH * sizeof(float));  // 1 KB

    hipMemsetAsync(d_ws, 0, BATCH * SE_CH * sizeof(float) + BATCH * sizeof(int),
                   stream);

    se_regpipe<<<NBLK, NTHR, 0, stream>>>(x, out, fc1_w, fc1_b,
                                          fc2_w, fc2_b, yacc, flags);
}